// Round 5
// baseline (4291.825 us; speedup 1.0000x reference)
//
#include <hip/hip_runtime.h>

#define T_STEPS 512
#define HID     128

typedef _Float16 v8hf __attribute__((ext_vector_type(8)));
typedef _Float16 v4hf __attribute__((ext_vector_type(4)));
typedef float v4f __attribute__((ext_vector_type(4)));

__device__ __forceinline__ float rcpf(float x) {
#if __has_builtin(__builtin_amdgcn_rcpf)
  return __builtin_amdgcn_rcpf(x);
#else
  return 1.0f / x;
#endif
}
__device__ __forceinline__ float sigm(float x)  { return rcpf(1.0f + __expf(-x)); }
__device__ __forceinline__ float tanh_f(float x){ return 1.0f - 2.0f * rcpf(__expf(2.0f * x) + 1.0f); }

// LDS-only barrier: wait own LDS ops, sync. Does NOT drain vmcnt —
// refill global_loads / flush global_stores stay in flight across it.
__device__ __forceinline__ void bar_lds() {
  asm volatile("s_waitcnt lgkmcnt(0)" ::: "memory");
  __builtin_amdgcn_s_barrier();
}

// Spin until *f >= need (relaxed polls), then agent-acquire fence so
// subsequent data loads see the producer's published stores.
// Safety valve: bounded spin -> worst case wrong answer, never a hang.
__device__ __forceinline__ void wait_flag(const int* f, int need) {
  int guard = 0;
  while (__hip_atomic_load(f, __ATOMIC_RELAXED, __HIP_MEMORY_SCOPE_AGENT) < need) {
    __builtin_amdgcn_s_sleep(8);
    if (++guard > (1 << 20)) break;
  }
  __builtin_amdgcn_fence(__ATOMIC_ACQUIRE, "agent");
}

// ---------------------------------------------------------------- prep ----
// Gate-interleaved rows: packed row r = 4*u + g  <->  orig row g*128 + u.
// Also zeroes the producer/consumer flags (graph replay re-runs this).
__global__ __launch_bounds__(256) void prep_w(
    const float* __restrict__ Wih0, const float* __restrict__ Whh0,
    const float* __restrict__ bih0, const float* __restrict__ bhh0,
    const float* __restrict__ Wih1, const float* __restrict__ Whh1,
    const float* __restrict__ bih1, const float* __restrict__ bhh1,
    _Float16* __restrict__ Wcat0, _Float16* __restrict__ Wcat1,
    float* __restrict__ bias0, float* __restrict__ bias1,
    int* __restrict__ flags) {
  int i = blockIdx.x * blockDim.x + threadIdx.x;
  if (i < 512 * 192) {                  // Wcat0 row r: [Wih0(64) | Whh0(128)]
    int r = i / 192, k = i - r * 192;
    int orig = (r & 3) * 128 + (r >> 2);
    float v = (k < 64) ? Wih0[orig * 64 + k] : Whh0[orig * 128 + (k - 64)];
    Wcat0[i] = (_Float16)v;
  }
  if (i < 512 * 256) {                  // Wcat1 row r: [Wih1(128) | Whh1(128)]
    int r = i >> 8, k = i & 255;
    int orig = (r & 3) * 128 + (r >> 2);
    float v = (k < 128) ? Wih1[orig * 128 + k] : Whh1[orig * 128 + (k - 128)];
    Wcat1[i] = (_Float16)v;
  }
  if (i < 512) {
    int orig = (i & 3) * 128 + (i >> 2);
    bias0[i] = bih0[orig] + bhh0[orig];
    bias1[i] = bih1[orig] + bhh1[orig];
  }
  if (i < 256) flags[i] = 0;
}

// ------------------------------------------------------ fused l0 + l1 ----
// 512 blocks x 512 threads, 2 blocks/CU (VGPR<=128, LDS 44 KiB).
// bid < 256: layer-0 producer for chains 2bid..2bid+1 (exact R2-l0 core);
//            publishes flags[bid] = #steps flushed to hs0 (release, agent)
//            after each 16-step flush batch.
// bid >= 256: layer-1 consumer of the same chains (exact R2-l1 core);
//            acquire-spins on flags before the initial fill and each refill.
// l1 trails l0 by ~40 steps; the two blocks' per-step overheads (~900 cyc
// of activation/LDS/barrier) overlap the partner block's MFMA issue.
__global__ __launch_bounds__(512, 4) void lstm_pc(
    const float*    __restrict__ x,      // [B][T][64] fp32
    const _Float16* __restrict__ Wcat0,  // [512][192] interleaved rows
    const float*    __restrict__ bias0,  // [512] interleaved
    const _Float16* __restrict__ Wcat1,  // [512][256] interleaved rows
    const float*    __restrict__ bias1,  // [512] interleaved
    _Float16*       __restrict__ hs0,    // [B][T][128]
    float*          __restrict__ h2last, // [B][128] fp32
    int*            __restrict__ flags) {
  __shared__ __align__(16) _Float16 xring[32][2][72];    // l0: 9216 B
  __shared__ __align__(16) _Float16 hist[32][2][HID];    // l0: 16384 B
  __shared__ __align__(16) _Float16 h0ring[32][2][136];  // l1: 17408 B
  __shared__ __align__(16) _Float16 hbuf[2][2][HID];     // both: 1024 B
  const int tid  = threadIdx.x;
  const int lane = tid & 63;
  const int wv   = tid >> 6;
  const int m    = lane & 15;
  const int q    = lane >> 4;
  const int ch   = m & 1;
  const int io   = (m >> 1) & 3;        // own output tile
  const int uown = wv * 16 + io * 4 + q; // own unit
  const bool writer = (m < 8);           // io covers 0..3 exactly once
  const int sc = tid >> 7, sd = tid & 127;
  const bool s1 = (io & 1) != 0, s2 = (io & 2) != 0;

  if (blockIdx.x < 256) {
    // ================================================== layer-0 role ====
    const int bid = blockIdx.x;
    const int b0  = bid * 2;

    v8hf aih[4][2], ahh[4][4];
    #pragma unroll
    for (int i = 0; i < 4; ++i) {
      const int rt = wv * 4 + i;
      #pragma unroll
      for (int kt = 0; kt < 2; ++kt)
        aih[i][kt] = *(const v8hf*)&Wcat0[(rt * 16 + m) * 192 + kt * 32 + q * 8];
      #pragma unroll
      for (int kt = 0; kt < 4; ++kt)
        ahh[i][kt] = *(const v8hf*)&Wcat0[(rt * 16 + m) * 192 + 64 + kt * 32 + q * 8];
    }
    v4f cb[4];
    #pragma unroll
    for (int i = 0; i < 4; ++i) {
      float4 b4 = *(const float4*)&bias0[(wv * 4 + i) * 16 + q * 4];
      cb[i][0] = b4.x; cb[i][1] = b4.y; cb[i][2] = b4.z; cb[i][3] = b4.w;
    }

    if (tid < 256) hbuf[0][sc][sd] = (_Float16)0.0f;  // h(-1)=0

    {  // ring fill steps 0..31: 512 items = 32 x 2ch x 8 segs
      const int s = tid >> 4, c = (tid >> 3) & 1, seg = tid & 7;
      const float* src = &x[((size_t)(b0 + c) * T_STEPS + s) * 64 + seg * 8];
      float4 a = *(const float4*)src;
      float4 b = *(const float4*)(src + 4);
      v8hf o;
      o[0] = (_Float16)a.x; o[1] = (_Float16)a.y; o[2] = (_Float16)a.z; o[3] = (_Float16)a.w;
      o[4] = (_Float16)b.x; o[5] = (_Float16)b.y; o[6] = (_Float16)b.z; o[7] = (_Float16)b.w;
      *(v8hf*)&xring[s][c][seg * 8] = o;
    }
    __syncthreads();

    float c_state = 0.0f;
    float4 ra{};   // refill staging (issue t%16==0, commit t%16==8)

    for (int t = 0; t < T_STEPS; ++t) {
      const int p = t & 1;
      if (((t & 15) == 0) && (t >= 16) && (t + 16 < T_STEPS)) {
        const int rs = t + 16 + (tid >> 5), c = (tid >> 4) & 1, s4 = tid & 15;
        ra = *(const float4*)&x[((size_t)(b0 + c) * T_STEPS + rs) * 64 + s4 * 4];
      }
      const bool flushstep = ((t & 15) == 8) && (t >= 24);
      if ((t & 15) == 8) {
        if (t >= 24 && t + 8 < T_STEPS) {  // commit refill to ring
          const int slot = (t + 8 + (tid >> 5)) & 31, c = (tid >> 4) & 1, s4 = tid & 15;
          v4hf o;
          o[0] = (_Float16)ra.x; o[1] = (_Float16)ra.y;
          o[2] = (_Float16)ra.z; o[3] = (_Float16)ra.w;
          *(v4hf*)&xring[slot][c][s4 * 4] = o;
        }
        if (t >= 24) {  // flush h steps t-24..t-9 to global
          const int fs = (t - 24) + (tid >> 5), fc = (tid >> 4) & 1, fseg = tid & 15;
          *(v8hf*)&hs0[((size_t)(b0 + fc) * T_STEPS + fs) * HID + fseg * 8] =
              *(const v8hf*)&hist[fs & 31][fc][fseg * 8];
        }
      }
      // gates(t) = bias + Wih*x(t) + Whh*h(t-1); all columns identical per ch
      v4f acc[4];
      #pragma unroll
      for (int i = 0; i < 4; ++i) acc[i] = cb[i];
      #pragma unroll
      for (int kt = 0; kt < 2; ++kt) {
        v8hf bfr = *(const v8hf*)&xring[t & 31][ch][kt * 32 + q * 8];
        #pragma unroll
        for (int i = 0; i < 4; ++i)
          acc[i] = __builtin_amdgcn_mfma_f32_16x16x32_f16(aih[i][kt], bfr, acc[i], 0, 0, 0);
      }
      #pragma unroll
      for (int kt = 0; kt < 4; ++kt) {
        v8hf bfr = *(const v8hf*)&hbuf[p][ch][kt * 32 + q * 8];
        #pragma unroll
        for (int i = 0; i < 4; ++i)
          acc[i] = __builtin_amdgcn_mfma_f32_16x16x32_f16(ahh[i][kt], bfr, acc[i], 0, 0, 0);
      }
      float g0, g1, g2, g3;
      {
        float a01, a23;
        a01 = s1 ? acc[1][0] : acc[0][0]; a23 = s1 ? acc[3][0] : acc[2][0];
        g0 = s2 ? a23 : a01;
        a01 = s1 ? acc[1][1] : acc[0][1]; a23 = s1 ? acc[3][1] : acc[2][1];
        g1 = s2 ? a23 : a01;
        a01 = s1 ? acc[1][2] : acc[0][2]; a23 = s1 ? acc[3][2] : acc[2][2];
        g2 = s2 ? a23 : a01;
        a01 = s1 ? acc[1][3] : acc[0][3]; a23 = s1 ? acc[3][3] : acc[2][3];
        g3 = s2 ? a23 : a01;
      }
      c_state = sigm(g1) * c_state + sigm(g0) * tanh_f(g2);
      const float hval = sigm(g3) * tanh_f(c_state);
      if (writer) {
        const _Float16 hh = (_Float16)hval;
        hbuf[1 - p][ch][uown] = hh;
        hist[t & 31][ch][uown] = hh;
      }
      // publish: drain stores (all waves) before barrier, then one release
      if (flushstep) asm volatile("s_waitcnt vmcnt(0)" ::: "memory");
      bar_lds();
      if (flushstep && tid == 0)
        __hip_atomic_store(&flags[bid], t - 8, __ATOMIC_RELEASE,
                           __HIP_MEMORY_SCOPE_AGENT);
    }
    {  // final flush: steps 496..511
      const int fs = 496 + (tid >> 5), fc = (tid >> 4) & 1, fseg = tid & 15;
      *(v8hf*)&hs0[((size_t)(b0 + fc) * T_STEPS + fs) * HID + fseg * 8] =
          *(const v8hf*)&hist[fs & 31][fc][fseg * 8];
    }
    asm volatile("s_waitcnt vmcnt(0)" ::: "memory");
    __syncthreads();
    if (tid == 0)
      __hip_atomic_store(&flags[bid], T_STEPS, __ATOMIC_RELEASE,
                         __HIP_MEMORY_SCOPE_AGENT);

  } else {
    // ================================================== layer-1 role ====
    const int bid = blockIdx.x - 256;
    const int b0  = bid * 2;
    const int* fl = &flags[bid];

    v8hf aih[4][4], ahh[4][4];
    #pragma unroll
    for (int i = 0; i < 4; ++i) {
      const int rt = wv * 4 + i;
      #pragma unroll
      for (int kt = 0; kt < 4; ++kt) {
        aih[i][kt] = *(const v8hf*)&Wcat1[(rt * 16 + m) * 256 + kt * 32 + q * 8];
        ahh[i][kt] = *(const v8hf*)&Wcat1[(rt * 16 + m) * 256 + 128 + kt * 32 + q * 8];
      }
    }
    v4f cb[4];
    #pragma unroll
    for (int i = 0; i < 4; ++i) {
      float4 b4 = *(const float4*)&bias1[(wv * 4 + i) * 16 + q * 4];
      cb[i][0] = b4.x; cb[i][1] = b4.y; cb[i][2] = b4.z; cb[i][3] = b4.w;
    }

    if (tid < 256) hbuf[0][sc][sd] = (_Float16)0.0f;

    wait_flag(fl, 32);                   // steps 0..31 flushed by producer
    {  // ring fill steps 0..31: 1024 items
      #pragma unroll
      for (int r = 0; r < 2; ++r) {
        const int it = tid + r * 512;
        const int s = it >> 5, c = (it >> 4) & 1, seg = it & 15;
        *(v8hf*)&h0ring[s][c][seg * 8] =
            *(const v8hf*)&hs0[((size_t)(b0 + c) * T_STEPS + s) * HID + seg * 8];
      }
    }
    __syncthreads();

    float c_state = 0.0f;
    v8hf rv{};

    for (int t = 0; t < T_STEPS; ++t) {
      const int p = t & 1;
      if (((t & 15) == 0) && (t >= 16) && (t + 16 < T_STEPS)) {  // refill issue
        wait_flag(fl, t + 32);
        const int rs = t + 16 + (tid >> 5), c = (tid >> 4) & 1, seg = tid & 15;
        rv = *(const v8hf*)&hs0[((size_t)(b0 + c) * T_STEPS + rs) * HID + seg * 8];
      }
      if (((t & 15) == 8) && (t >= 24) && (t + 8 < T_STEPS)) {   // refill commit
        const int slot = (t + 8 + (tid >> 5)) & 31, c = (tid >> 4) & 1, seg = tid & 15;
        *(v8hf*)&h0ring[slot][c][seg * 8] = rv;
      }
      v4f acc[4];
      #pragma unroll
      for (int i = 0; i < 4; ++i) acc[i] = cb[i];
      #pragma unroll
      for (int kt = 0; kt < 4; ++kt) {
        v8hf bfr = *(const v8hf*)&h0ring[t & 31][ch][kt * 32 + q * 8];
        #pragma unroll
        for (int i = 0; i < 4; ++i)
          acc[i] = __builtin_amdgcn_mfma_f32_16x16x32_f16(aih[i][kt], bfr, acc[i], 0, 0, 0);
      }
      #pragma unroll
      for (int kt = 0; kt < 4; ++kt) {
        v8hf bfr = *(const v8hf*)&hbuf[p][ch][kt * 32 + q * 8];
        #pragma unroll
        for (int i = 0; i < 4; ++i)
          acc[i] = __builtin_amdgcn_mfma_f32_16x16x32_f16(ahh[i][kt], bfr, acc[i], 0, 0, 0);
      }
      float g0, g1, g2, g3;
      {
        float a01, a23;
        a01 = s1 ? acc[1][0] : acc[0][0]; a23 = s1 ? acc[3][0] : acc[2][0];
        g0 = s2 ? a23 : a01;
        a01 = s1 ? acc[1][1] : acc[0][1]; a23 = s1 ? acc[3][1] : acc[2][1];
        g1 = s2 ? a23 : a01;
        a01 = s1 ? acc[1][2] : acc[0][2]; a23 = s1 ? acc[3][2] : acc[2][2];
        g2 = s2 ? a23 : a01;
        a01 = s1 ? acc[1][3] : acc[0][3]; a23 = s1 ? acc[3][3] : acc[2][3];
        g3 = s2 ? a23 : a01;
      }
      c_state = sigm(g1) * c_state + sigm(g0) * tanh_f(g2);
      const float hval = sigm(g3) * tanh_f(c_state);
      if (writer) {
        hbuf[1 - p][ch][uown] = (_Float16)hval;
        if (t == T_STEPS - 1) h2last[(size_t)(b0 + ch) * HID + uown] = hval;
      }
      bar_lds();
    }
  }
}

// ------------------------------------------------------------- fc head ----
__global__ __launch_bounds__(128) void fc_head(
    const float* __restrict__ h2last, const float* __restrict__ fc1w,
    const float* __restrict__ fc1b, const float* __restrict__ fc2w,
    const float* __restrict__ fc2b, float* __restrict__ out) {
  __shared__ float hb[128];
  __shared__ float part[2];
  const int b = blockIdx.x, j = threadIdx.x;
  hb[j] = h2last[(size_t)b * HID + j];
  __syncthreads();
  const float* wr = fc1w + j * HID;
  float acc = 0.f;
  #pragma unroll 8
  for (int d = 0; d < HID; ++d) acc += wr[d] * hb[d];
  float v = fmaxf(acc + fc1b[j], 0.f) * fc2w[j];
  #pragma unroll
  for (int s = 32; s > 0; s >>= 1) v += __shfl_down(v, s);
  if ((j & 63) == 0) part[j >> 6] = v;
  __syncthreads();
  if (j == 0) out[b] = part[0] + part[1] + fc2b[0];
}

// -------------------------------------------------------------- launch ----
extern "C" void kernel_launch(void* const* d_in, const int* in_sizes, int n_in,
                              void* d_out, int out_size, void* d_ws, size_t ws_size,
                              hipStream_t stream) {
  const float* x    = (const float*)d_in[0];
  const float* Wih0 = (const float*)d_in[1];
  const float* Whh0 = (const float*)d_in[2];
  const float* bih0 = (const float*)d_in[3];
  const float* bhh0 = (const float*)d_in[4];
  const float* Wih1 = (const float*)d_in[5];
  const float* Whh1 = (const float*)d_in[6];
  const float* bih1 = (const float*)d_in[7];
  const float* bhh1 = (const float*)d_in[8];
  const float* fc1w = (const float*)d_in[9];
  const float* fc1b = (const float*)d_in[10];
  const float* fc2w = (const float*)d_in[11];
  const float* fc2b = (const float*)d_in[12];
  float* out = (float*)d_out;

  char* ws = (char*)d_ws;
  const size_t OFF_HS0 = 0;                    // 512*512*128*2 = 64 MiB
  const size_t OFF_WC0 = 67108864;             // 512*192*2
  const size_t OFF_WC1 = OFF_WC0 + 196608;     // 512*256*2
  const size_t OFF_B0  = OFF_WC1 + 262144;     // 512*4
  const size_t OFF_B1  = OFF_B0 + 2048;
  const size_t OFF_H2L = OFF_B1 + 2048;        // 512*128*4
  const size_t OFF_FLG = OFF_H2L + 262144;     // 256*4

  _Float16* hs0    = (_Float16*)(ws + OFF_HS0);
  _Float16* Wcat0  = (_Float16*)(ws + OFF_WC0);
  _Float16* Wcat1  = (_Float16*)(ws + OFF_WC1);
  float*    bias0  = (float*)(ws + OFF_B0);
  float*    bias1  = (float*)(ws + OFF_B1);
  float*    h2last = (float*)(ws + OFF_H2L);
  int*      flags  = (int*)(ws + OFF_FLG);

  prep_w<<<512, 256, 0, stream>>>(Wih0, Whh0, bih0, bhh0, Wih1, Whh1, bih1, bhh1,
                                  Wcat0, Wcat1, bias0, bias1, flags);
  lstm_pc<<<512, 512, 0, stream>>>(x, Wcat0, bias0, Wcat1, bias1, hs0, h2last, flags);
  fc_head<<<512, 128, 0, stream>>>(h2last, fc1w, fc1b, fc2w, fc2b, out);
}

// Round 9
// 713.601 us; speedup vs baseline: 6.0143x; 6.0143x over previous
//
#include <hip/hip_runtime.h>

#define T_STEPS 512
#define HID     128
#define PSTR    516   // P-ring row stride (f32): 16B-aligned, bank-spread

typedef _Float16 v8hf __attribute__((ext_vector_type(8)));
typedef _Float16 v4hf __attribute__((ext_vector_type(4)));
typedef float v4f __attribute__((ext_vector_type(4)));

__device__ __forceinline__ float rcpf(float x) {
#if __has_builtin(__builtin_amdgcn_rcpf)
  return __builtin_amdgcn_rcpf(x);
#else
  return 1.0f / x;
#endif
}
__device__ __forceinline__ float sigm(float x)  { return rcpf(1.0f + __expf(-x)); }
__device__ __forceinline__ float tanh_f(float x){ return 1.0f - 2.0f * rcpf(__expf(2.0f * x) + 1.0f); }

// LDS-only barrier: wait own LDS ops, sync. Does NOT drain vmcnt —
// refill global_loads / flush global_stores stay in flight across it.
__device__ __forceinline__ void bar_lds() {
  asm volatile("s_waitcnt lgkmcnt(0)" ::: "memory");
  __builtin_amdgcn_s_barrier();
}

// ---------------------------------------------------------------- prep ----
// Gate-interleaved rows: packed row r = 4*u + g  <->  orig row g*128 + u.
__global__ __launch_bounds__(256) void prep_w(
    const float* __restrict__ Wih0, const float* __restrict__ Whh0,
    const float* __restrict__ bih0, const float* __restrict__ bhh0,
    const float* __restrict__ Wih1, const float* __restrict__ Whh1,
    const float* __restrict__ bih1, const float* __restrict__ bhh1,
    _Float16* __restrict__ Wcat0, _Float16* __restrict__ Wcat1,
    float* __restrict__ bias0, float* __restrict__ bias1) {
  int i = blockIdx.x * blockDim.x + threadIdx.x;
  if (i < 512 * 192) {                  // Wcat0 row r: [Wih0(64) | Whh0(128)]
    int r = i / 192, k = i - r * 192;
    int orig = (r & 3) * 128 + (r >> 2);
    float v = (k < 64) ? Wih0[orig * 64 + k] : Whh0[orig * 128 + (k - 64)];
    Wcat0[i] = (_Float16)v;
  }
  if (i < 512 * 256) {                  // Wcat1 row r: [Wih1(128) | Whh1(128)]
    int r = i >> 8, k = i & 255;
    int orig = (r & 3) * 128 + (r >> 2);
    float v = (k < 128) ? Wih1[orig * 128 + k] : Whh1[orig * 128 + (k - 128)];
    Wcat1[i] = (_Float16)v;
  }
  if (i < 512) {
    int orig = (i & 3) * 128 + (i >> 2);
    bias0[i] = bih0[orig] + bhh0[orig];
    bias1[i] = bih1[orig] + bhh1[orig];
  }
}

// ------------------------------------------------------------- layer 0 ----
// R2 single-phase chassis. Per step: 16 recurrent MFMAs (C-init = prefetched
// projection fragment from the LDS P-ring) + in-register activation.
// Every 16 steps (t%16==9): batched x-proj GEMM for steps t+7..t+22
// (cols = 16 steps, mtiles = 2 ch; bias folded as C-init) -> P-ring.
// P-ring rows stride PSTR=516 f32: aligned v4f, conflict-free broadcast
// reads; slot arithmetic keeps batch writes disjoint from live reads.
__global__ __launch_bounds__(512, 2) void lstm_l0(
    const float*    __restrict__ x,     // [B][T][64] fp32
    const _Float16* __restrict__ Wcat,  // [512][192] interleaved rows
    const float*    __restrict__ bias,  // [512] interleaved
    _Float16*       __restrict__ hs0) { // [B][T][128]
  __shared__ __align__(16) _Float16 xring[32][2][72];    // 9216 B
  __shared__ __align__(16) _Float16 hist[32][2][HID];    // 16384 B
  __shared__ __align__(16) _Float16 hbuf[2][2][HID];     // 1024 B
  __shared__ __align__(16) float    pring[2][32][PSTR];  // 132096 B
  const int tid  = threadIdx.x;
  const int lane = tid & 63;
  const int wv   = tid >> 6;
  const int m    = lane & 15;
  const int q    = lane >> 4;
  const int ch   = m & 1;
  const int io   = (m >> 1) & 3;        // own output tile
  const int uown = wv * 16 + io * 4 + q; // own unit
  const bool writer = (m < 8);           // io covers 0..3 exactly once
  const int b0   = blockIdx.x * 2;

  v8hf aih[4][2], ahh[4][4];
  #pragma unroll
  for (int i = 0; i < 4; ++i) {
    const int rt = wv * 4 + i;
    #pragma unroll
    for (int kt = 0; kt < 2; ++kt)
      aih[i][kt] = *(const v8hf*)&Wcat[(rt * 16 + m) * 192 + kt * 32 + q * 8];
    #pragma unroll
    for (int kt = 0; kt < 4; ++kt)
      ahh[i][kt] = *(const v8hf*)&Wcat[(rt * 16 + m) * 192 + 64 + kt * 32 + q * 8];
  }
  v4f cb[4];
  #pragma unroll
  for (int i = 0; i < 4; ++i) {
    float4 b4 = *(const float4*)&bias[(wv * 4 + i) * 16 + q * 4];
    cb[i][0] = b4.x; cb[i][1] = b4.y; cb[i][2] = b4.z; cb[i][3] = b4.w;
  }

  if (tid < 256) hbuf[0][tid >> 7][tid & 127] = (_Float16)0.0f;  // h(-1)=0

  {  // ring fill steps 0..31: 512 items = 32 x 2ch x 8 segs
    const int s = tid >> 4, c = (tid >> 3) & 1, seg = tid & 7;
    const float* src = &x[((size_t)(b0 + c) * T_STEPS + s) * 64 + seg * 8];
    float4 a = *(const float4*)src;
    float4 b = *(const float4*)(src + 4);
    v8hf o;
    o[0] = (_Float16)a.x; o[1] = (_Float16)a.y; o[2] = (_Float16)a.z; o[3] = (_Float16)a.w;
    o[4] = (_Float16)b.x; o[5] = (_Float16)b.y; o[6] = (_Float16)b.z; o[7] = (_Float16)b.w;
    *(v8hf*)&xring[s][c][seg * 8] = o;
  }
  __syncthreads();

  {  // pre-loop batch: proj for steps 0..15 -> P-ring
    #pragma unroll
    for (int ct = 0; ct < 2; ++ct) {
      v4f a2[4];
      #pragma unroll
      for (int i = 0; i < 4; ++i) a2[i] = cb[i];
      #pragma unroll
      for (int kt = 0; kt < 2; ++kt) {
        v8hf bfr = *(const v8hf*)&xring[m][ct][kt * 32 + q * 8];
        #pragma unroll
        for (int i = 0; i < 4; ++i)
          a2[i] = __builtin_amdgcn_mfma_f32_16x16x32_f16(aih[i][kt], bfr, a2[i], 0, 0, 0);
      }
      #pragma unroll
      for (int i = 0; i < 4; ++i)
        *(v4f*)&pring[ct][m][(wv * 4 + i) * 16 + q * 4] = a2[i];
    }
  }
  __syncthreads();

  v4f pcn[4];   // prefetched projection C-fragments for the next step
  #pragma unroll
  for (int i = 0; i < 4; ++i)
    pcn[i] = *(const v4f*)&pring[ch][0][(wv * 4 + i) * 16 + q * 4];

  float c_state = 0.0f;
  float4 ra{};   // refill staging (issue t%16==0, commit t%16==8)
  const bool s1 = (io & 1) != 0, s2 = (io & 2) != 0;

  for (int t = 0; t < T_STEPS; ++t) {
    const int p = t & 1;
    // refill issue: x steps t+16..t+31 -> regs (512 thr x float4)
    if (((t & 15) == 0) && (t >= 16) && (t + 16 < T_STEPS)) {
      const int rs = t + 16 + (tid >> 5), c = (tid >> 4) & 1, s4 = tid & 15;
      ra = *(const float4*)&x[((size_t)(b0 + c) * T_STEPS + rs) * 64 + s4 * 4];
    }
    if ((t & 15) == 8) {
      if (t >= 24 && t + 8 < T_STEPS) {  // commit refill to ring
        const int slot = (t + 8 + (tid >> 5)) & 31, c = (tid >> 4) & 1, s4 = tid & 15;
        v4hf o;
        o[0] = (_Float16)ra.x; o[1] = (_Float16)ra.y;
        o[2] = (_Float16)ra.z; o[3] = (_Float16)ra.w;
        *(v4hf*)&xring[slot][c][s4 * 4] = o;
      }
      if (t >= 24) {  // flush h steps t-24..t-9 to global
        const int fs = (t - 24) + (tid >> 5), fc = (tid >> 4) & 1, fseg = tid & 15;
        *(v8hf*)&hs0[((size_t)(b0 + fc) * T_STEPS + fs) * HID + fseg * 8] =
            *(const v8hf*)&hist[fs & 31][fc][fseg * 8];
      }
    }
    // recurrent MFMA: acc = P[t] (C-init, prefetched) + Whh * h(t-1)
    v4f acc[4];
    #pragma unroll
    for (int kt = 0; kt < 4; ++kt) {
      v8hf bfr = *(const v8hf*)&hbuf[p][ch][kt * 32 + q * 8];
      #pragma unroll
      for (int i = 0; i < 4; ++i)
        acc[i] = __builtin_amdgcn_mfma_f32_16x16x32_f16(
            ahh[i][kt], bfr, (kt == 0) ? pcn[i] : acc[i], 0, 0, 0);
    }
    // batch x-proj GEMM for steps t+7..t+22 (ring stable: commit was t-1)
    if (((t & 15) == 9) && (t + 7 < T_STEPS)) {
      const int sb0 = t + 7;
      #pragma unroll
      for (int ct = 0; ct < 2; ++ct) {
        v4f a2[4];
        #pragma unroll
        for (int i = 0; i < 4; ++i) a2[i] = cb[i];
        #pragma unroll
        for (int kt = 0; kt < 2; ++kt) {
          v8hf bfr = *(const v8hf*)&xring[(sb0 + m) & 31][ct][kt * 32 + q * 8];
          #pragma unroll
          for (int i = 0; i < 4; ++i)
            a2[i] = __builtin_amdgcn_mfma_f32_16x16x32_f16(aih[i][kt], bfr, a2[i], 0, 0, 0);
        }
        #pragma unroll
        for (int i = 0; i < 4; ++i)
          *(v4f*)&pring[ct][(sb0 + m) & 31][(wv * 4 + i) * 16 + q * 4] = a2[i];
      }
    }
    // prefetch next step's projection C-fragments (slot (t+1)&31 is stable)
    #pragma unroll
    for (int i = 0; i < 4; ++i)
      pcn[i] = *(const v4f*)&pring[ch][(t + 1) & 31][(wv * 4 + i) * 16 + q * 4];
    // select own tile + activation (all lanes; writer lanes store)
    float g0, g1, g2, g3;
    {
      float a01, a23;
      a01 = s1 ? acc[1][0] : acc[0][0]; a23 = s1 ? acc[3][0] : acc[2][0];
      g0 = s2 ? a23 : a01;
      a01 = s1 ? acc[1][1] : acc[0][1]; a23 = s1 ? acc[3][1] : acc[2][1];
      g1 = s2 ? a23 : a01;
      a01 = s1 ? acc[1][2] : acc[0][2]; a23 = s1 ? acc[3][2] : acc[2][2];
      g2 = s2 ? a23 : a01;
      a01 = s1 ? acc[1][3] : acc[0][3]; a23 = s1 ? acc[3][3] : acc[2][3];
      g3 = s2 ? a23 : a01;
    }
    c_state = sigm(g1) * c_state + sigm(g0) * tanh_f(g2);
    const float hval = sigm(g3) * tanh_f(c_state);
    if (writer) {
      const _Float16 hh = (_Float16)hval;
      hbuf[1 - p][ch][uown] = hh;
      hist[t & 31][ch][uown] = hh;
    }
    bar_lds();
  }
  {  // final flush: steps 496..511
    const int fs = 496 + (tid >> 5), fc = (tid >> 4) & 1, fseg = tid & 15;
    *(v8hf*)&hs0[((size_t)(b0 + fc) * T_STEPS + fs) * HID + fseg * 8] =
        *(const v8hf*)&hist[fs & 31][fc][fseg * 8];
  }
}

// ------------------------------------------------------------- layer 1 ----
// Same chassis; batch projection input is h0 (K=128) from the padded ring.
__global__ __launch_bounds__(512, 2) void lstm_l1(
    const _Float16* __restrict__ hs0,   // [B][T][128]
    const _Float16* __restrict__ Wcat,  // [512][256] interleaved rows
    const float*    __restrict__ bias,  // [512] interleaved
    float*          __restrict__ h2last) { // [B][128] fp32
  __shared__ __align__(16) _Float16 h0ring[32][2][136];  // 17408 B
  __shared__ __align__(16) _Float16 hbuf[2][2][HID];     // 1024 B
  __shared__ __align__(16) float    pring[2][32][PSTR];  // 132096 B
  const int tid  = threadIdx.x;
  const int lane = tid & 63;
  const int wv   = tid >> 6;
  const int m    = lane & 15;
  const int q    = lane >> 4;
  const int ch   = m & 1;
  const int io   = (m >> 1) & 3;
  const int uown = wv * 16 + io * 4 + q;
  const bool writer = (m < 8);
  const int b0   = blockIdx.x * 2;

  v8hf aih[4][4], ahh[4][4];
  #pragma unroll
  for (int i = 0; i < 4; ++i) {
    const int rt = wv * 4 + i;
    #pragma unroll
    for (int kt = 0; kt < 4; ++kt) {
      aih[i][kt] = *(const v8hf*)&Wcat[(rt * 16 + m) * 256 + kt * 32 + q * 8];
      ahh[i][kt] = *(const v8hf*)&Wcat[(rt * 16 + m) * 256 + 128 + kt * 32 + q * 8];
    }
  }
  v4f cb[4];
  #pragma unroll
  for (int i = 0; i < 4; ++i) {
    float4 b4 = *(const float4*)&bias[(wv * 4 + i) * 16 + q * 4];
    cb[i][0] = b4.x; cb[i][1] = b4.y; cb[i][2] = b4.z; cb[i][3] = b4.w;
  }

  if (tid < 256) hbuf[0][tid >> 7][tid & 127] = (_Float16)0.0f;

  {  // ring fill steps 0..31: 1024 items
    #pragma unroll
    for (int r = 0; r < 2; ++r) {
      const int it = tid + r * 512;
      const int s = it >> 5, c = (it >> 4) & 1, seg = it & 15;
      *(v8hf*)&h0ring[s][c][seg * 8] =
          *(const v8hf*)&hs0[((size_t)(b0 + c) * T_STEPS + s) * HID + seg * 8];
    }
  }
  __syncthreads();

  {  // pre-loop batch: proj for steps 0..15 -> P-ring
    #pragma unroll
    for (int ct = 0; ct < 2; ++ct) {
      v4f a2[4];
      #pragma unroll
      for (int i = 0; i < 4; ++i) a2[i] = cb[i];
      #pragma unroll
      for (int kt = 0; kt < 4; ++kt) {
        v8hf bfr = *(const v8hf*)&h0ring[m][ct][kt * 32 + q * 8];
        #pragma unroll
        for (int i = 0; i < 4; ++i)
          a2[i] = __builtin_amdgcn_mfma_f32_16x16x32_f16(aih[i][kt], bfr, a2[i], 0, 0, 0);
      }
      #pragma unroll
      for (int i = 0; i < 4; ++i)
        *(v4f*)&pring[ct][m][(wv * 4 + i) * 16 + q * 4] = a2[i];
    }
  }
  __syncthreads();

  v4f pcn[4];
  #pragma unroll
  for (int i = 0; i < 4; ++i)
    pcn[i] = *(const v4f*)&pring[ch][0][(wv * 4 + i) * 16 + q * 4];

  float c_state = 0.0f;
  v8hf rv{};
  const bool s1 = (io & 1) != 0, s2 = (io & 2) != 0;

  for (int t = 0; t < T_STEPS; ++t) {
    const int p = t & 1;
    if (((t & 15) == 0) && (t >= 16) && (t + 16 < T_STEPS)) {  // refill issue
      const int rs = t + 16 + (tid >> 5), c = (tid >> 4) & 1, seg = tid & 15;
      rv = *(const v8hf*)&hs0[((size_t)(b0 + c) * T_STEPS + rs) * HID + seg * 8];
    }
    if (((t & 15) == 8) && (t >= 24) && (t + 8 < T_STEPS)) {   // refill commit
      const int slot = (t + 8 + (tid >> 5)) & 31, c = (tid >> 4) & 1, seg = tid & 15;
      *(v8hf*)&h0ring[slot][c][seg * 8] = rv;
    }
    // recurrent MFMA: acc = P[t] + Whh * h1(t-1)
    v4f acc[4];
    #pragma unroll
    for (int kt = 0; kt < 4; ++kt) {
      v8hf bfr = *(const v8hf*)&hbuf[p][ch][kt * 32 + q * 8];
      #pragma unroll
      for (int i = 0; i < 4; ++i)
        acc[i] = __builtin_amdgcn_mfma_f32_16x16x32_f16(
            ahh[i][kt], bfr, (kt == 0) ? pcn[i] : acc[i], 0, 0, 0);
    }
    // batch h0-proj GEMM for steps t+7..t+22
    if (((t & 15) == 9) && (t + 7 < T_STEPS)) {
      const int sb0 = t + 7;
      #pragma unroll
      for (int ct = 0; ct < 2; ++ct) {
        v4f a2[4];
        #pragma unroll
        for (int i = 0; i < 4; ++i) a2[i] = cb[i];
        #pragma unroll
        for (int kt = 0; kt < 4; ++kt) {
          v8hf bfr = *(const v8hf*)&h0ring[(sb0 + m) & 31][ct][kt * 32 + q * 8];
          #pragma unroll
          for (int i = 0; i < 4; ++i)
            a2[i] = __builtin_amdgcn_mfma_f32_16x16x32_f16(aih[i][kt], bfr, a2[i], 0, 0, 0);
        }
        #pragma unroll
        for (int i = 0; i < 4; ++i)
          *(v4f*)&pring[ct][(sb0 + m) & 31][(wv * 4 + i) * 16 + q * 4] = a2[i];
      }
    }
    // prefetch next step's projection C-fragments
    #pragma unroll
    for (int i = 0; i < 4; ++i)
      pcn[i] = *(const v4f*)&pring[ch][(t + 1) & 31][(wv * 4 + i) * 16 + q * 4];
    float g0, g1, g2, g3;
    {
      float a01, a23;
      a01 = s1 ? acc[1][0] : acc[0][0]; a23 = s1 ? acc[3][0] : acc[2][0];
      g0 = s2 ? a23 : a01;
      a01 = s1 ? acc[1][1] : acc[0][1]; a23 = s1 ? acc[3][1] : acc[2][1];
      g1 = s2 ? a23 : a01;
      a01 = s1 ? acc[1][2] : acc[0][2]; a23 = s1 ? acc[3][2] : acc[2][2];
      g2 = s2 ? a23 : a01;
      a01 = s1 ? acc[1][3] : acc[0][3]; a23 = s1 ? acc[3][3] : acc[2][3];
      g3 = s2 ? a23 : a01;
    }
    c_state = sigm(g1) * c_state + sigm(g0) * tanh_f(g2);
    const float hval = sigm(g3) * tanh_f(c_state);
    if (writer) {
      hbuf[1 - p][ch][uown] = (_Float16)hval;
      if (t == T_STEPS - 1) h2last[(size_t)(b0 + ch) * HID + uown] = hval;
    }
    bar_lds();
  }
}

// ------------------------------------------------------------- fc head ----
__global__ __launch_bounds__(128) void fc_head(
    const float* __restrict__ h2last, const float* __restrict__ fc1w,
    const float* __restrict__ fc1b, const float* __restrict__ fc2w,
    const float* __restrict__ fc2b, float* __restrict__ out) {
  __shared__ float hb[128];
  __shared__ float part[2];
  const int b = blockIdx.x, j = threadIdx.x;
  hb[j] = h2last[(size_t)b * HID + j];
  __syncthreads();
  const float* wr = fc1w + j * HID;
  float acc = 0.f;
  #pragma unroll 8
  for (int d = 0; d < HID; ++d) acc += wr[d] * hb[d];
  float v = fmaxf(acc + fc1b[j], 0.f) * fc2w[j];
  #pragma unroll
  for (int s = 32; s > 0; s >>= 1) v += __shfl_down(v, s);
  if ((j & 63) == 0) part[j >> 6] = v;
  __syncthreads();
  if (j == 0) out[b] = part[0] + part[1] + fc2b[0];
}

// -------------------------------------------------------------- launch ----
extern "C" void kernel_launch(void* const* d_in, const int* in_sizes, int n_in,
                              void* d_out, int out_size, void* d_ws, size_t ws_size,
                              hipStream_t stream) {
  const float* x    = (const float*)d_in[0];
  const float* Wih0 = (const float*)d_in[1];
  const float* Whh0 = (const float*)d_in[2];
  const float* bih0 = (const float*)d_in[3];
  const float* bhh0 = (const float*)d_in[4];
  const float* Wih1 = (const float*)d_in[5];
  const float* Whh1 = (const float*)d_in[6];
  const float* bih1 = (const float*)d_in[7];
  const float* bhh1 = (const float*)d_in[8];
  const float* fc1w = (const float*)d_in[9];
  const float* fc1b = (const float*)d_in[10];
  const float* fc2w = (const float*)d_in[11];
  const float* fc2b = (const float*)d_in[12];
  float* out = (float*)d_out;

  char* ws = (char*)d_ws;
  const size_t OFF_HS0 = 0;                    // 512*512*128*2 = 64 MiB
  const size_t OFF_WC0 = 67108864;             // 512*192*2
  const size_t OFF_WC1 = OFF_WC0 + 196608;     // 512*256*2
  const size_t OFF_B0  = OFF_WC1 + 262144;     // 512*4
  const size_t OFF_B1  = OFF_B0 + 2048;
  const size_t OFF_H2L = OFF_B1 + 2048;        // 512*128*4

  _Float16* hs0    = (_Float16*)(ws + OFF_HS0);
  _Float16* Wcat0  = (_Float16*)(ws + OFF_WC0);
  _Float16* Wcat1  = (_Float16*)(ws + OFF_WC1);
  float*    bias0  = (float*)(ws + OFF_B0);
  float*    bias1  = (float*)(ws + OFF_B1);
  float*    h2last = (float*)(ws + OFF_H2L);

  prep_w<<<512, 256, 0, stream>>>(Wih0, Whh0, bih0, bhh0, Wih1, Whh1, bih1, bhh1,
                                  Wcat0, Wcat1, bias0, bias1);
  lstm_l0<<<256, 512, 0, stream>>>(x, Wcat0, bias0, hs0);
  lstm_l1<<<256, 512, 0, stream>>>(hs0, Wcat1, bias1, h2last);
  fc_head<<<512, 128, 0, stream>>>(h2last, fc1w, fc1b, fc2w, fc2b, out);
}

// Round 10
// 547.995 us; speedup vs baseline: 7.8319x; 1.3022x over previous
//
#include <hip/hip_runtime.h>

#define T_STEPS 512
#define HID     128

typedef _Float16 v8hf __attribute__((ext_vector_type(8)));
typedef _Float16 v4hf __attribute__((ext_vector_type(4)));
typedef float v4f __attribute__((ext_vector_type(4)));

__device__ __forceinline__ float rcpf(float x) {
#if __has_builtin(__builtin_amdgcn_rcpf)
  return __builtin_amdgcn_rcpf(x);
#else
  return 1.0f / x;
#endif
}
__device__ __forceinline__ float sigm(float x)  { return rcpf(1.0f + __expf(-x)); }
__device__ __forceinline__ float tanh_f(float x){ return 1.0f - 2.0f * rcpf(__expf(2.0f * x) + 1.0f); }

// LDS-only barrier: wait own LDS ops, sync. Does NOT drain vmcnt.
__device__ __forceinline__ void bar_lds() {
  asm volatile("s_waitcnt lgkmcnt(0)" ::: "memory");
  __builtin_amdgcn_s_barrier();
}

// Spin until *f >= need (relaxed polls), then agent-acquire fence.
// Bounded spin: worst case wrong answer, never a hang.
__device__ __forceinline__ void wait_flag(const int* f, int need) {
  int guard = 0;
  while (__hip_atomic_load(f, __ATOMIC_RELAXED, __HIP_MEMORY_SCOPE_AGENT) < need) {
    __builtin_amdgcn_s_sleep(8);
    if (++guard > (1 << 20)) break;
  }
  __builtin_amdgcn_fence(__ATOMIC_ACQUIRE, "agent");
}

// ---------------------------------------------------------------- prep ----
// Gate-interleaved rows: packed row r = 4*u + g  <->  orig row g*128 + u.
// Also zeroes producer/consumer flags (graph replay re-runs this).
__global__ __launch_bounds__(256) void prep_w(
    const float* __restrict__ Wih0, const float* __restrict__ Whh0,
    const float* __restrict__ bih0, const float* __restrict__ bhh0,
    const float* __restrict__ Wih1, const float* __restrict__ Whh1,
    const float* __restrict__ bih1, const float* __restrict__ bhh1,
    _Float16* __restrict__ Wcat0, _Float16* __restrict__ Wcat1,
    float* __restrict__ bias0, float* __restrict__ bias1,
    int* __restrict__ flags) {
  int i = blockIdx.x * blockDim.x + threadIdx.x;
  if (i < 512 * 192) {                  // Wcat0 row r: [Wih0(64) | Whh0(128)]
    int r = i / 192, k = i - r * 192;
    int orig = (r & 3) * 128 + (r >> 2);
    float v = (k < 64) ? Wih0[orig * 64 + k] : Whh0[orig * 128 + (k - 64)];
    Wcat0[i] = (_Float16)v;
  }
  if (i < 512 * 256) {                  // Wcat1 row r: [Wih1(128) | Whh1(128)]
    int r = i >> 8, k = i & 255;
    int orig = (r & 3) * 128 + (r >> 2);
    float v = (k < 128) ? Wih1[orig * 128 + k] : Whh1[orig * 128 + (k - 128)];
    Wcat1[i] = (_Float16)v;
  }
  if (i < 512) {
    int orig = (i & 3) * 128 + (i >> 2);
    bias0[i] = bih0[orig] + bhh0[orig];
    bias1[i] = bih1[orig] + bhh1[orig];
  }
  if (i < 128) flags[i] = 0;
}

// ------------------------------------------------------ fused l0 + l1 ----
// 256 blocks x 512 threads, 1 block/CU (VGPR cap 512 via bounds(512,1) ->
// no spill possible; LDS 90 KB). 4 chains/block: cols = 4 ch x 4 io.
// bid < 128 : layer-0 producer for chains 4bid..4bid+3 (R2 chassis,
//             per-step ih+hh MFMA); publishes flags[bid] = #steps in hs0.
// bid >= 128: layer-1 consumer of the same chains; acquire-spins on flags
//             before initial fill and each refill. l1 trails l0 by ~40
//             steps; the roles' walls overlap -> ~512+skew step-times
//             total instead of 1024.
__global__ __launch_bounds__(512, 1) void lstm_pc(
    const float*    __restrict__ x,      // [B][T][64] fp32
    const _Float16* __restrict__ Wcat0,  // [512][192] interleaved rows
    const float*    __restrict__ bias0,  // [512] interleaved
    const _Float16* __restrict__ Wcat1,  // [512][256] interleaved rows
    const float*    __restrict__ bias1,  // [512] interleaved
    _Float16*       __restrict__ hs0,    // [B][T][128]
    float*          __restrict__ h2last, // [B][128] fp32
    int*            __restrict__ flags) {
  __shared__ __align__(16) _Float16 xring[32][4][72];    // l0: 18432 B
  __shared__ __align__(16) _Float16 hist[32][4][HID];    // l0: 32768 B
  __shared__ __align__(16) _Float16 h0ring[32][4][136];  // l1: 34816 B
  __shared__ __align__(16) _Float16 hbuf[2][4][136];     // both: 2176 B (padded)
  const int tid  = threadIdx.x;
  const int lane = tid & 63;
  const int wv   = tid >> 6;
  const int m    = lane & 15;
  const int q    = lane >> 4;
  const int ch   = m & 3;               // chain 0..3
  const int io   = m >> 2;              // own output tile 0..3
  const int uown = wv * 16 + io * 4 + q; // own unit
  const bool s1 = (io & 1) != 0, s2 = (io & 2) != 0;

  if (blockIdx.x < 128) {
    // ================================================== layer-0 role ====
    const int bid = blockIdx.x;
    const int b0  = bid * 4;

    v8hf aih[4][2], ahh[4][4];
    #pragma unroll
    for (int i = 0; i < 4; ++i) {
      const int rt = wv * 4 + i;
      #pragma unroll
      for (int kt = 0; kt < 2; ++kt)
        aih[i][kt] = *(const v8hf*)&Wcat0[(rt * 16 + m) * 192 + kt * 32 + q * 8];
      #pragma unroll
      for (int kt = 0; kt < 4; ++kt)
        ahh[i][kt] = *(const v8hf*)&Wcat0[(rt * 16 + m) * 192 + 64 + kt * 32 + q * 8];
    }
    v4f cb[4];
    #pragma unroll
    for (int i = 0; i < 4; ++i) {
      float4 b4 = *(const float4*)&bias0[(wv * 4 + i) * 16 + q * 4];
      cb[i][0] = b4.x; cb[i][1] = b4.y; cb[i][2] = b4.z; cb[i][3] = b4.w;
    }

    hbuf[0][ch][uown] = (_Float16)0.0f;  // h(-1)=0 (every lane owns a unit)

    {  // ring fill steps 0..31: 1024 items = 32 s x 4 ch x 8 segs(8 f16)
      #pragma unroll
      for (int r = 0; r < 2; ++r) {
        const int it = tid + r * 512;
        const int s = it >> 5, rem = it & 31, c = rem >> 3, seg = rem & 7;
        const float* src = &x[((size_t)(b0 + c) * T_STEPS + s) * 64 + seg * 8];
        float4 a = *(const float4*)src;
        float4 b = *(const float4*)(src + 4);
        v8hf o;
        o[0] = (_Float16)a.x; o[1] = (_Float16)a.y; o[2] = (_Float16)a.z; o[3] = (_Float16)a.w;
        o[4] = (_Float16)b.x; o[5] = (_Float16)b.y; o[6] = (_Float16)b.z; o[7] = (_Float16)b.w;
        *(v8hf*)&xring[s][c][seg * 8] = o;
      }
    }
    __syncthreads();

    float c_state = 0.0f;
    float4 ra{}, rb{};   // refill staging (issue t%16==0, commit t%16==8)

    for (int t = 0; t < T_STEPS; ++t) {
      const int p = t & 1;
      if (((t & 15) == 0) && (t >= 16) && (t + 16 < T_STEPS)) {  // refill issue
        const int rs = t + 16 + (tid >> 5), rem = tid & 31;
        const int c = rem >> 3, seg = rem & 7;
        const float* src = &x[((size_t)(b0 + c) * T_STEPS + rs) * 64 + seg * 8];
        ra = *(const float4*)src;
        rb = *(const float4*)(src + 4);
      }
      const bool flushstep = ((t & 15) == 8) && (t >= 24);
      if ((t & 15) == 8) {
        if (t >= 24 && t + 8 < T_STEPS) {  // commit refill to ring
          const int slot = (t + 8 + (tid >> 5)) & 31, rem = tid & 31;
          const int c = rem >> 3, seg = rem & 7;
          v8hf o;
          o[0] = (_Float16)ra.x; o[1] = (_Float16)ra.y; o[2] = (_Float16)ra.z; o[3] = (_Float16)ra.w;
          o[4] = (_Float16)rb.x; o[5] = (_Float16)rb.y; o[6] = (_Float16)rb.z; o[7] = (_Float16)rb.w;
          *(v8hf*)&xring[slot][c][seg * 8] = o;
        }
        if (t >= 24) {  // flush h steps t-24..t-9 (16 st x 4 ch x 128)
          const int fs = (t - 24) + (tid >> 5), rem = tid & 31;
          const int fc = rem >> 3, fseg = rem & 7;
          const size_t gb = ((size_t)(b0 + fc) * T_STEPS + fs) * HID + fseg * 16;
          *(v8hf*)&hs0[gb]     = *(const v8hf*)&hist[fs & 31][fc][fseg * 16];
          *(v8hf*)&hs0[gb + 8] = *(const v8hf*)&hist[fs & 31][fc][fseg * 16 + 8];
        }
      }
      // gates(t) = bias + Wih*x(t) + Whh*h(t-1); col carries chain ch
      v4f acc[4];
      #pragma unroll
      for (int i = 0; i < 4; ++i) acc[i] = cb[i];
      #pragma unroll
      for (int kt = 0; kt < 2; ++kt) {
        v8hf bfr = *(const v8hf*)&xring[t & 31][ch][kt * 32 + q * 8];
        #pragma unroll
        for (int i = 0; i < 4; ++i)
          acc[i] = __builtin_amdgcn_mfma_f32_16x16x32_f16(aih[i][kt], bfr, acc[i], 0, 0, 0);
      }
      #pragma unroll
      for (int kt = 0; kt < 4; ++kt) {
        v8hf bfr = *(const v8hf*)&hbuf[p][ch][kt * 32 + q * 8];
        #pragma unroll
        for (int i = 0; i < 4; ++i)
          acc[i] = __builtin_amdgcn_mfma_f32_16x16x32_f16(ahh[i][kt], bfr, acc[i], 0, 0, 0);
      }
      float g0, g1, g2, g3;
      {
        float a01, a23;
        a01 = s1 ? acc[1][0] : acc[0][0]; a23 = s1 ? acc[3][0] : acc[2][0];
        g0 = s2 ? a23 : a01;
        a01 = s1 ? acc[1][1] : acc[0][1]; a23 = s1 ? acc[3][1] : acc[2][1];
        g1 = s2 ? a23 : a01;
        a01 = s1 ? acc[1][2] : acc[0][2]; a23 = s1 ? acc[3][2] : acc[2][2];
        g2 = s2 ? a23 : a01;
        a01 = s1 ? acc[1][3] : acc[0][3]; a23 = s1 ? acc[3][3] : acc[2][3];
        g3 = s2 ? a23 : a01;
      }
      c_state = sigm(g1) * c_state + sigm(g0) * tanh_f(g2);
      const float hval = sigm(g3) * tanh_f(c_state);
      {
        const _Float16 hh = (_Float16)hval;
        hbuf[1 - p][ch][uown] = hh;
        hist[t & 31][ch][uown] = hh;
      }
      if (flushstep) asm volatile("s_waitcnt vmcnt(0)" ::: "memory");
      bar_lds();
      if (flushstep && tid == 0)
        __hip_atomic_store(&flags[bid], t - 8, __ATOMIC_RELEASE,
                           __HIP_MEMORY_SCOPE_AGENT);
    }
    {  // final flush: steps 496..511
      const int fs = 496 + (tid >> 5), rem = tid & 31;
      const int fc = rem >> 3, fseg = rem & 7;
      const size_t gb = ((size_t)(b0 + fc) * T_STEPS + fs) * HID + fseg * 16;
      *(v8hf*)&hs0[gb]     = *(const v8hf*)&hist[fs & 31][fc][fseg * 16];
      *(v8hf*)&hs0[gb + 8] = *(const v8hf*)&hist[fs & 31][fc][fseg * 16 + 8];
    }
    asm volatile("s_waitcnt vmcnt(0)" ::: "memory");
    __syncthreads();
    if (tid == 0)
      __hip_atomic_store(&flags[bid], T_STEPS, __ATOMIC_RELEASE,
                         __HIP_MEMORY_SCOPE_AGENT);

  } else {
    // ================================================== layer-1 role ====
    const int bid = blockIdx.x - 128;
    const int b0  = bid * 4;
    const int* fl = &flags[bid];

    v8hf aih[4][4], ahh[4][4];
    #pragma unroll
    for (int i = 0; i < 4; ++i) {
      const int rt = wv * 4 + i;
      #pragma unroll
      for (int kt = 0; kt < 4; ++kt) {
        aih[i][kt] = *(const v8hf*)&Wcat1[(rt * 16 + m) * 256 + kt * 32 + q * 8];
        ahh[i][kt] = *(const v8hf*)&Wcat1[(rt * 16 + m) * 256 + 128 + kt * 32 + q * 8];
      }
    }
    v4f cb[4];
    #pragma unroll
    for (int i = 0; i < 4; ++i) {
      float4 b4 = *(const float4*)&bias1[(wv * 4 + i) * 16 + q * 4];
      cb[i][0] = b4.x; cb[i][1] = b4.y; cb[i][2] = b4.z; cb[i][3] = b4.w;
    }

    hbuf[0][ch][uown] = (_Float16)0.0f;

    wait_flag(fl, 32);                   // steps 0..31 flushed by producer
    {  // ring fill steps 0..31: 1024 items x 16 f16
      #pragma unroll
      for (int r = 0; r < 2; ++r) {
        const int it = tid + r * 512;
        const int s = it >> 5, rem = it & 31, c = rem >> 3, seg = rem & 7;
        const size_t gb = ((size_t)(b0 + c) * T_STEPS + s) * HID + seg * 16;
        *(v8hf*)&h0ring[s][c][seg * 16]     = *(const v8hf*)&hs0[gb];
        *(v8hf*)&h0ring[s][c][seg * 16 + 8] = *(const v8hf*)&hs0[gb + 8];
      }
    }
    __syncthreads();

    float c_state = 0.0f;
    v8hf rv0{}, rv1{};

    for (int t = 0; t < T_STEPS; ++t) {
      const int p = t & 1;
      if (((t & 15) == 0) && (t >= 16) && (t + 16 < T_STEPS)) {  // refill issue
        wait_flag(fl, t + 32);
        const int rs = t + 16 + (tid >> 5), rem = tid & 31;
        const int c = rem >> 3, seg = rem & 7;
        const size_t gb = ((size_t)(b0 + c) * T_STEPS + rs) * HID + seg * 16;
        rv0 = *(const v8hf*)&hs0[gb];
        rv1 = *(const v8hf*)&hs0[gb + 8];
      }
      if (((t & 15) == 8) && (t >= 24) && (t + 8 < T_STEPS)) {   // refill commit
        const int slot = (t + 8 + (tid >> 5)) & 31, rem = tid & 31;
        const int c = rem >> 3, seg = rem & 7;
        *(v8hf*)&h0ring[slot][c][seg * 16]     = rv0;
        *(v8hf*)&h0ring[slot][c][seg * 16 + 8] = rv1;
      }
      v4f acc[4];
      #pragma unroll
      for (int i = 0; i < 4; ++i) acc[i] = cb[i];
      #pragma unroll
      for (int kt = 0; kt < 4; ++kt) {
        v8hf bfr = *(const v8hf*)&h0ring[t & 31][ch][kt * 32 + q * 8];
        #pragma unroll
        for (int i = 0; i < 4; ++i)
          acc[i] = __builtin_amdgcn_mfma_f32_16x16x32_f16(aih[i][kt], bfr, acc[i], 0, 0, 0);
      }
      #pragma unroll
      for (int kt = 0; kt < 4; ++kt) {
        v8hf bfr = *(const v8hf*)&hbuf[p][ch][kt * 32 + q * 8];
        #pragma unroll
        for (int i = 0; i < 4; ++i)
          acc[i] = __builtin_amdgcn_mfma_f32_16x16x32_f16(ahh[i][kt], bfr, acc[i], 0, 0, 0);
      }
      float g0, g1, g2, g3;
      {
        float a01, a23;
        a01 = s1 ? acc[1][0] : acc[0][0]; a23 = s1 ? acc[3][0] : acc[2][0];
        g0 = s2 ? a23 : a01;
        a01 = s1 ? acc[1][1] : acc[0][1]; a23 = s1 ? acc[3][1] : acc[2][1];
        g1 = s2 ? a23 : a01;
        a01 = s1 ? acc[1][2] : acc[0][2]; a23 = s1 ? acc[3][2] : acc[2][2];
        g2 = s2 ? a23 : a01;
        a01 = s1 ? acc[1][3] : acc[0][3]; a23 = s1 ? acc[3][3] : acc[2][3];
        g3 = s2 ? a23 : a01;
      }
      c_state = sigm(g1) * c_state + sigm(g0) * tanh_f(g2);
      const float hval = sigm(g3) * tanh_f(c_state);
      hbuf[1 - p][ch][uown] = (_Float16)hval;
      if (t == T_STEPS - 1) h2last[(size_t)(b0 + ch) * HID + uown] = hval;
      bar_lds();
    }
  }
}

// ------------------------------------------------------------- fc head ----
__global__ __launch_bounds__(128) void fc_head(
    const float* __restrict__ h2last, const float* __restrict__ fc1w,
    const float* __restrict__ fc1b, const float* __restrict__ fc2w,
    const float* __restrict__ fc2b, float* __restrict__ out) {
  __shared__ float hb[128];
  __shared__ float part[2];
  const int b = blockIdx.x, j = threadIdx.x;
  hb[j] = h2last[(size_t)b * HID + j];
  __syncthreads();
  const float* wr = fc1w + j * HID;
  float acc = 0.f;
  #pragma unroll 8
  for (int d = 0; d < HID; ++d) acc += wr[d] * hb[d];
  float v = fmaxf(acc + fc1b[j], 0.f) * fc2w[j];
  #pragma unroll
  for (int s = 32; s > 0; s >>= 1) v += __shfl_down(v, s);
  if ((j & 63) == 0) part[j >> 6] = v;
  __syncthreads();
  if (j == 0) out[b] = part[0] + part[1] + fc2b[0];
}

// -------------------------------------------------------------- launch ----
extern "C" void kernel_launch(void* const* d_in, const int* in_sizes, int n_in,
                              void* d_out, int out_size, void* d_ws, size_t ws_size,
                              hipStream_t stream) {
  const float* x    = (const float*)d_in[0];
  const float* Wih0 = (const float*)d_in[1];
  const float* Whh0 = (const float*)d_in[2];
  const float* bih0 = (const float*)d_in[3];
  const float* bhh0 = (const float*)d_in[4];
  const float* Wih1 = (const float*)d_in[5];
  const float* Whh1 = (const float*)d_in[6];
  const float* bih1 = (const float*)d_in[7];
  const float* bhh1 = (const float*)d_in[8];
  const float* fc1w = (const float*)d_in[9];
  const float* fc1b = (const float*)d_in[10];
  const float* fc2w = (const float*)d_in[11];
  const float* fc2b = (const float*)d_in[12];
  float* out = (float*)d_out;

  char* ws = (char*)d_ws;
  const size_t OFF_HS0 = 0;                    // 512*512*128*2 = 64 MiB
  const size_t OFF_WC0 = 67108864;             // 512*192*2
  const size_t OFF_WC1 = OFF_WC0 + 196608;     // 512*256*2
  const size_t OFF_B0  = OFF_WC1 + 262144;     // 512*4
  const size_t OFF_B1  = OFF_B0 + 2048;
  const size_t OFF_H2L = OFF_B1 + 2048;        // 512*128*4
  const size_t OFF_FLG = OFF_H2L + 262144;     // 128*4

  _Float16* hs0    = (_Float16*)(ws + OFF_HS0);
  _Float16* Wcat0  = (_Float16*)(ws + OFF_WC0);
  _Float16* Wcat1  = (_Float16*)(ws + OFF_WC1);
  float*    bias0  = (float*)(ws + OFF_B0);
  float*    bias1  = (float*)(ws + OFF_B1);
  float*    h2last = (float*)(ws + OFF_H2L);
  int*      flags  = (int*)(ws + OFF_FLG);

  prep_w<<<512, 256, 0, stream>>>(Wih0, Whh0, bih0, bhh0, Wih1, Whh1, bih1, bhh1,
                                  Wcat0, Wcat1, bias0, bias1, flags);
  lstm_pc<<<256, 512, 0, stream>>>(x, Wcat0, bias0, Wcat1, bias1, hs0, h2last, flags);
  fc_head<<<512, 128, 0, stream>>>(h2last, fc1w, fc1b, fc2w, fc2b, out);
}

// Round 11
// 536.998 us; speedup vs baseline: 7.9923x; 1.0205x over previous
//
#include <hip/hip_runtime.h>

#define T_STEPS 512
#define HID     128
#define PSLOT   516    // pring slot stride (f32): 16B-aligned, bank-spread
#define PCH     6200   // pring chain stride (f32): 12*516 + 8

typedef _Float16 v8hf __attribute__((ext_vector_type(8)));
typedef _Float16 v4hf __attribute__((ext_vector_type(4)));
typedef float v4f __attribute__((ext_vector_type(4)));

__device__ __forceinline__ float rcpf(float x) {
#if __has_builtin(__builtin_amdgcn_rcpf)
  return __builtin_amdgcn_rcpf(x);
#else
  return 1.0f / x;
#endif
}
__device__ __forceinline__ float sigm(float x)  { return rcpf(1.0f + __expf(-x)); }
__device__ __forceinline__ float tanh_f(float x){ return 1.0f - 2.0f * rcpf(__expf(2.0f * x) + 1.0f); }

// LDS-only barrier: wait own LDS ops, sync. Does NOT drain vmcnt.
__device__ __forceinline__ void bar_lds() {
  asm volatile("s_waitcnt lgkmcnt(0)" ::: "memory");
  __builtin_amdgcn_s_barrier();
}

// Spin until *f >= need (relaxed polls), then agent-acquire fence.
// Bounded spin: worst case wrong answer, never a hang.
__device__ __forceinline__ void wait_flag(const int* f, int need) {
  int guard = 0;
  while (__hip_atomic_load(f, __ATOMIC_RELAXED, __HIP_MEMORY_SCOPE_AGENT) < need) {
    __builtin_amdgcn_s_sleep(8);
    if (++guard > (1 << 20)) break;
  }
  __builtin_amdgcn_fence(__ATOMIC_ACQUIRE, "agent");
}

// ---------------------------------------------------------------- prep ----
__global__ __launch_bounds__(256) void prep_w(
    const float* __restrict__ Wih0, const float* __restrict__ Whh0,
    const float* __restrict__ bih0, const float* __restrict__ bhh0,
    const float* __restrict__ Wih1, const float* __restrict__ Whh1,
    const float* __restrict__ bih1, const float* __restrict__ bhh1,
    _Float16* __restrict__ Wcat0, _Float16* __restrict__ Wcat1,
    float* __restrict__ bias0, float* __restrict__ bias1,
    int* __restrict__ flags) {
  int i = blockIdx.x * blockDim.x + threadIdx.x;
  if (i < 512 * 192) {                  // Wcat0 row r: [Wih0(64) | Whh0(128)]
    int r = i / 192, k = i - r * 192;
    int orig = (r & 3) * 128 + (r >> 2);
    float v = (k < 64) ? Wih0[orig * 64 + k] : Whh0[orig * 128 + (k - 64)];
    Wcat0[i] = (_Float16)v;
  }
  if (i < 512 * 256) {                  // Wcat1 row r: [Wih1(128) | Whh1(128)]
    int r = i >> 8, k = i & 255;
    int orig = (r & 3) * 128 + (r >> 2);
    float v = (k < 128) ? Wih1[orig * 128 + k] : Whh1[orig * 128 + (k - 128)];
    Wcat1[i] = (_Float16)v;
  }
  if (i < 512) {
    int orig = (i & 3) * 128 + (i >> 2);
    bias0[i] = bih0[orig] + bhh0[orig];
    bias1[i] = bih1[orig] + bhh1[orig];
  }
  if (i < 128) flags[i] = 0;
}

// ------------------------------------------------------ fused l0 + l1 ----
// 256 blocks x 512 threads, 1 block/CU. 4 chains/block; cols = 4 sb x 4 ch
// (sb doubles as the batch-step slot AND the io tile-select at activation).
// Per step: 16 hh-MFMAs with C-init = prefetched P fragment from the f32
// P-ring (12 slots). Every 4 steps (t%4==3): one batch GEMM pass computes
// the ih-projection for steps t+5..t+8 x 4 chains at full col utilization.
// Slot math (mod 12): pass writes (t+5..t+8)%12; reads touch t%12,(t+1)%12
// -> disjoint for every phase class. LDS overlaid per role on one buffer:
// l0 = xring+hist+hbuf+pring = 149 KB, l1 = h0ring+hbuf+pring = 133 KB.
__global__ __launch_bounds__(512, 1) void lstm_pc(
    const float*    __restrict__ x,      // [B][T][64] fp32
    const _Float16* __restrict__ Wcat0,  // [512][192] interleaved rows
    const float*    __restrict__ bias0,  // [512] interleaved
    const _Float16* __restrict__ Wcat1,  // [512][256] interleaved rows
    const float*    __restrict__ bias1,  // [512] interleaved
    _Float16*       __restrict__ hs0,    // [B][T][128]
    float*          __restrict__ h2last, // [B][128] fp32
    int*            __restrict__ flags) {
  __shared__ __align__(16) char smem[152576];
  const int tid  = threadIdx.x;
  const int lane = tid & 63;
  const int wv   = tid >> 6;
  const int m    = lane & 15;
  const int q    = lane >> 4;
  const int ch   = m & 3;               // chain 0..3
  const int io   = m >> 2;              // output tile select / batch sb 0..3
  const int uown = wv * 16 + io * 4 + q; // own unit
  const bool s1 = (io & 1) != 0, s2 = (io & 2) != 0;
  const int pbase = ch * PCH + (wv * 4) * 16 + q * 4;  // pring lane base (i=0)

  if (blockIdx.x < 128) {
    // ================================================== layer-0 role ====
    const int bid = blockIdx.x;
    const int b0  = bid * 4;
    _Float16 (*xring)[4][72]  = (_Float16 (*)[4][72])(smem);            // 18432
    _Float16 (*hist)[4][HID]  = (_Float16 (*)[4][HID])(smem + 18432);   // 32768
    _Float16 (*hbuf)[4][136]  = (_Float16 (*)[4][136])(smem + 51200);   // 2176
    float*    pring           = (float*)(smem + 53376);                 // 99200

    v8hf aih[4][2], ahh[4][4];
    #pragma unroll
    for (int i = 0; i < 4; ++i) {
      const int rt = wv * 4 + i;
      #pragma unroll
      for (int kt = 0; kt < 2; ++kt)
        aih[i][kt] = *(const v8hf*)&Wcat0[(rt * 16 + m) * 192 + kt * 32 + q * 8];
      #pragma unroll
      for (int kt = 0; kt < 4; ++kt)
        ahh[i][kt] = *(const v8hf*)&Wcat0[(rt * 16 + m) * 192 + 64 + kt * 32 + q * 8];
    }
    v4f cb[4];
    #pragma unroll
    for (int i = 0; i < 4; ++i) {
      float4 b4 = *(const float4*)&bias0[(wv * 4 + i) * 16 + q * 4];
      cb[i][0] = b4.x; cb[i][1] = b4.y; cb[i][2] = b4.z; cb[i][3] = b4.w;
    }

    hbuf[0][ch][uown] = (_Float16)0.0f;  // h(-1)=0

    {  // ring fill steps 0..31: 1024 items = 32 s x 4 ch x 8 segs
      #pragma unroll
      for (int r = 0; r < 2; ++r) {
        const int it = tid + r * 512;
        const int s = it >> 5, rem = it & 31, c = rem >> 3, seg = rem & 7;
        const float* src = &x[((size_t)(b0 + c) * T_STEPS + s) * 64 + seg * 8];
        float4 a = *(const float4*)src;
        float4 b = *(const float4*)(src + 4);
        v8hf o;
        o[0] = (_Float16)a.x; o[1] = (_Float16)a.y; o[2] = (_Float16)a.z; o[3] = (_Float16)a.w;
        o[4] = (_Float16)b.x; o[5] = (_Float16)b.y; o[6] = (_Float16)b.z; o[7] = (_Float16)b.w;
        *(v8hf*)&xring[s][c][seg * 8] = o;
      }
    }
    __syncthreads();

    {  // pre-passes: projections for steps 0..7 -> pring slots 0..7
      #pragma unroll
      for (int pb = 0; pb < 8; pb += 4) {
        v4f a2[4];
        #pragma unroll
        for (int i = 0; i < 4; ++i) a2[i] = cb[i];
        #pragma unroll
        for (int kt = 0; kt < 2; ++kt) {
          v8hf bfr = *(const v8hf*)&xring[pb + io][ch][kt * 32 + q * 8];
          #pragma unroll
          for (int i = 0; i < 4; ++i)
            a2[i] = __builtin_amdgcn_mfma_f32_16x16x32_f16(aih[i][kt], bfr, a2[i], 0, 0, 0);
        }
        #pragma unroll
        for (int i = 0; i < 4; ++i)
          *(v4f*)&pring[pbase + (pb + io) * PSLOT + i * 16] = a2[i];
      }
    }
    __syncthreads();

    v4f pcn[4];   // prefetched P fragments for the next step
    #pragma unroll
    for (int i = 0; i < 4; ++i)
      pcn[i] = *(const v4f*)&pring[pbase + 0 * PSLOT + i * 16];

    float c_state = 0.0f;
    float4 ra{}, rb{};   // refill staging

    for (int t = 0; t < T_STEPS; ++t) {
      const int p = t & 1;
      if (((t & 15) == 0) && (t >= 16) && (t + 16 < T_STEPS)) {  // refill issue
        const int rs = t + 16 + (tid >> 5), rem = tid & 31;
        const int c = rem >> 3, seg = rem & 7;
        const float* src = &x[((size_t)(b0 + c) * T_STEPS + rs) * 64 + seg * 8];
        ra = *(const float4*)src;
        rb = *(const float4*)(src + 4);
      }
      const bool flushstep = ((t & 15) == 8) && (t >= 24);
      if ((t & 15) == 8) {
        if (t >= 24 && t + 8 < T_STEPS) {  // commit refill to ring
          const int slot = (t + 8 + (tid >> 5)) & 31, rem = tid & 31;
          const int c = rem >> 3, seg = rem & 7;
          v8hf o;
          o[0] = (_Float16)ra.x; o[1] = (_Float16)ra.y; o[2] = (_Float16)ra.z; o[3] = (_Float16)ra.w;
          o[4] = (_Float16)rb.x; o[5] = (_Float16)rb.y; o[6] = (_Float16)rb.z; o[7] = (_Float16)rb.w;
          *(v8hf*)&xring[slot][c][seg * 8] = o;
        }
        if (t >= 24) {  // flush h steps t-24..t-9
          const int fs = (t - 24) + (tid >> 5), rem = tid & 31;
          const int fc = rem >> 3, fseg = rem & 7;
          const size_t gb = ((size_t)(b0 + fc) * T_STEPS + fs) * HID + fseg * 16;
          *(v8hf*)&hs0[gb]     = *(const v8hf*)&hist[fs & 31][fc][fseg * 16];
          *(v8hf*)&hs0[gb + 8] = *(const v8hf*)&hist[fs & 31][fc][fseg * 16 + 8];
        }
      }
      // hh-MFMA: acc = P[t] (C-init, prefetched) + Whh*h(t-1)
      v4f acc[4];
      #pragma unroll
      for (int kt = 0; kt < 4; ++kt) {
        v8hf bfr = *(const v8hf*)&hbuf[p][ch][kt * 32 + q * 8];
        #pragma unroll
        for (int i = 0; i < 4; ++i)
          acc[i] = __builtin_amdgcn_mfma_f32_16x16x32_f16(
              ahh[i][kt], bfr, (kt == 0) ? pcn[i] : acc[i], 0, 0, 0);
      }
      // batch pass: ih-proj for steps t+5..t+8 (4 sb cols x 4 chains)
      if (((t & 3) == 3) && (t + 5 < T_STEPS)) {
        const int base = t + 5;
        const int s32  = (base + io) & 31;
        int r12 = (base % 12) + io; if (r12 >= 12) r12 -= 12;
        v4f a2[4];
        #pragma unroll
        for (int i = 0; i < 4; ++i) a2[i] = cb[i];
        #pragma unroll
        for (int kt = 0; kt < 2; ++kt) {
          v8hf bfr = *(const v8hf*)&xring[s32][ch][kt * 32 + q * 8];
          #pragma unroll
          for (int i = 0; i < 4; ++i)
            a2[i] = __builtin_amdgcn_mfma_f32_16x16x32_f16(aih[i][kt], bfr, a2[i], 0, 0, 0);
        }
        #pragma unroll
        for (int i = 0; i < 4; ++i)
          *(v4f*)&pring[pbase + r12 * PSLOT + i * 16] = a2[i];
      }
      // prefetch next step's P fragments (slot (t+1)%12 is stable)
      {
        const int rs = (t + 1) % 12;
        #pragma unroll
        for (int i = 0; i < 4; ++i)
          pcn[i] = *(const v4f*)&pring[pbase + rs * PSLOT + i * 16];
      }
      float g0, g1, g2, g3;
      {
        float a01, a23;
        a01 = s1 ? acc[1][0] : acc[0][0]; a23 = s1 ? acc[3][0] : acc[2][0];
        g0 = s2 ? a23 : a01;
        a01 = s1 ? acc[1][1] : acc[0][1]; a23 = s1 ? acc[3][1] : acc[2][1];
        g1 = s2 ? a23 : a01;
        a01 = s1 ? acc[1][2] : acc[0][2]; a23 = s1 ? acc[3][2] : acc[2][2];
        g2 = s2 ? a23 : a01;
        a01 = s1 ? acc[1][3] : acc[0][3]; a23 = s1 ? acc[3][3] : acc[2][3];
        g3 = s2 ? a23 : a01;
      }
      c_state = sigm(g1) * c_state + sigm(g0) * tanh_f(g2);
      const float hval = sigm(g3) * tanh_f(c_state);
      {
        const _Float16 hh = (_Float16)hval;
        hbuf[1 - p][ch][uown] = hh;
        hist[t & 31][ch][uown] = hh;
      }
      if (flushstep) asm volatile("s_waitcnt vmcnt(0)" ::: "memory");
      bar_lds();
      if (flushstep && tid == 0)
        __hip_atomic_store(&flags[bid], t - 8, __ATOMIC_RELEASE,
                           __HIP_MEMORY_SCOPE_AGENT);
    }
    {  // final flush: steps 496..511
      const int fs = 496 + (tid >> 5), rem = tid & 31;
      const int fc = rem >> 3, fseg = rem & 7;
      const size_t gb = ((size_t)(b0 + fc) * T_STEPS + fs) * HID + fseg * 16;
      *(v8hf*)&hs0[gb]     = *(const v8hf*)&hist[fs & 31][fc][fseg * 16];
      *(v8hf*)&hs0[gb + 8] = *(const v8hf*)&hist[fs & 31][fc][fseg * 16 + 8];
    }
    asm volatile("s_waitcnt vmcnt(0)" ::: "memory");
    __syncthreads();
    if (tid == 0)
      __hip_atomic_store(&flags[bid], T_STEPS, __ATOMIC_RELEASE,
                         __HIP_MEMORY_SCOPE_AGENT);

  } else {
    // ================================================== layer-1 role ====
    const int bid = blockIdx.x - 128;
    const int b0  = bid * 4;
    const int* fl = &flags[bid];
    _Float16 (*h0ring)[4][136] = (_Float16 (*)[4][136])(smem);          // 34816
    _Float16 (*hbuf)[4][136]   = (_Float16 (*)[4][136])(smem + 34816);  // 2176
    float*    pring            = (float*)(smem + 36992);                // 99200

    v8hf aih[4][4], ahh[4][4];
    #pragma unroll
    for (int i = 0; i < 4; ++i) {
      const int rt = wv * 4 + i;
      #pragma unroll
      for (int kt = 0; kt < 4; ++kt) {
        aih[i][kt] = *(const v8hf*)&Wcat1[(rt * 16 + m) * 256 + kt * 32 + q * 8];
        ahh[i][kt] = *(const v8hf*)&Wcat1[(rt * 16 + m) * 256 + 128 + kt * 32 + q * 8];
      }
    }
    v4f cb[4];
    #pragma unroll
    for (int i = 0; i < 4; ++i) {
      float4 b4 = *(const float4*)&bias1[(wv * 4 + i) * 16 + q * 4];
      cb[i][0] = b4.x; cb[i][1] = b4.y; cb[i][2] = b4.z; cb[i][3] = b4.w;
    }

    hbuf[0][ch][uown] = (_Float16)0.0f;

    wait_flag(fl, 32);                   // steps 0..31 flushed by producer
    {  // ring fill steps 0..31
      #pragma unroll
      for (int r = 0; r < 2; ++r) {
        const int it = tid + r * 512;
        const int s = it >> 5, rem = it & 31, c = rem >> 3, seg = rem & 7;
        const size_t gb = ((size_t)(b0 + c) * T_STEPS + s) * HID + seg * 16;
        *(v8hf*)&h0ring[s][c][seg * 16]     = *(const v8hf*)&hs0[gb];
        *(v8hf*)&h0ring[s][c][seg * 16 + 8] = *(const v8hf*)&hs0[gb + 8];
      }
    }
    __syncthreads();

    {  // pre-passes: projections for steps 0..7 -> pring slots 0..7
      #pragma unroll
      for (int pb = 0; pb < 8; pb += 4) {
        v4f a2[4];
        #pragma unroll
        for (int i = 0; i < 4; ++i) a2[i] = cb[i];
        #pragma unroll
        for (int kt = 0; kt < 4; ++kt) {
          v8hf bfr = *(const v8hf*)&h0ring[pb + io][ch][kt * 32 + q * 8];
          #pragma unroll
          for (int i = 0; i < 4; ++i)
            a2[i] = __builtin_amdgcn_mfma_f32_16x16x32_f16(aih[i][kt], bfr, a2[i], 0, 0, 0);
        }
        #pragma unroll
        for (int i = 0; i < 4; ++i)
          *(v4f*)&pring[pbase + (pb + io) * PSLOT + i * 16] = a2[i];
      }
    }
    __syncthreads();

    v4f pcn[4];
    #pragma unroll
    for (int i = 0; i < 4; ++i)
      pcn[i] = *(const v4f*)&pring[pbase + 0 * PSLOT + i * 16];

    float c_state = 0.0f;
    v8hf rv0{}, rv1{};

    for (int t = 0; t < T_STEPS; ++t) {
      const int p = t & 1;
      if (((t & 15) == 0) && (t >= 16) && (t + 16 < T_STEPS)) {  // refill issue
        wait_flag(fl, t + 32);
        const int rs = t + 16 + (tid >> 5), rem = tid & 31;
        const int c = rem >> 3, seg = rem & 7;
        const size_t gb = ((size_t)(b0 + c) * T_STEPS + rs) * HID + seg * 16;
        rv0 = *(const v8hf*)&hs0[gb];
        rv1 = *(const v8hf*)&hs0[gb + 8];
      }
      if (((t & 15) == 8) && (t >= 24) && (t + 8 < T_STEPS)) {   // refill commit
        const int slot = (t + 8 + (tid >> 5)) & 31, rem = tid & 31;
        const int c = rem >> 3, seg = rem & 7;
        *(v8hf*)&h0ring[slot][c][seg * 16]     = rv0;
        *(v8hf*)&h0ring[slot][c][seg * 16 + 8] = rv1;
      }
      // hh-MFMA: acc = P[t] + Whh*h1(t-1)
      v4f acc[4];
      #pragma unroll
      for (int kt = 0; kt < 4; ++kt) {
        v8hf bfr = *(const v8hf*)&hbuf[p][ch][kt * 32 + q * 8];
        #pragma unroll
        for (int i = 0; i < 4; ++i)
          acc[i] = __builtin_amdgcn_mfma_f32_16x16x32_f16(
              ahh[i][kt], bfr, (kt == 0) ? pcn[i] : acc[i], 0, 0, 0);
      }
      // batch pass: h0-proj for steps t+5..t+8
      if (((t & 3) == 3) && (t + 5 < T_STEPS)) {
        const int base = t + 5;
        const int s32  = (base + io) & 31;
        int r12 = (base % 12) + io; if (r12 >= 12) r12 -= 12;
        v4f a2[4];
        #pragma unroll
        for (int i = 0; i < 4; ++i) a2[i] = cb[i];
        #pragma unroll
        for (int kt = 0; kt < 4; ++kt) {
          v8hf bfr = *(const v8hf*)&h0ring[s32][ch][kt * 32 + q * 8];
          #pragma unroll
          for (int i = 0; i < 4; ++i)
            a2[i] = __builtin_amdgcn_mfma_f32_16x16x32_f16(aih[i][kt], bfr, a2[i], 0, 0, 0);
        }
        #pragma unroll
        for (int i = 0; i < 4; ++i)
          *(v4f*)&pring[pbase + r12 * PSLOT + i * 16] = a2[i];
      }
      {
        const int rs = (t + 1) % 12;
        #pragma unroll
        for (int i = 0; i < 4; ++i)
          pcn[i] = *(const v4f*)&pring[pbase + rs * PSLOT + i * 16];
      }
      float g0, g1, g2, g3;
      {
        float a01, a23;
        a01 = s1 ? acc[1][0] : acc[0][0]; a23 = s1 ? acc[3][0] : acc[2][0];
        g0 = s2 ? a23 : a01;
        a01 = s1 ? acc[1][1] : acc[0][1]; a23 = s1 ? acc[3][1] : acc[2][1];
        g1 = s2 ? a23 : a01;
        a01 = s1 ? acc[1][2] : acc[0][2]; a23 = s1 ? acc[3][2] : acc[2][2];
        g2 = s2 ? a23 : a01;
        a01 = s1 ? acc[1][3] : acc[0][3]; a23 = s1 ? acc[3][3] : acc[2][3];
        g3 = s2 ? a23 : a01;
      }
      c_state = sigm(g1) * c_state + sigm(g0) * tanh_f(g2);
      const float hval = sigm(g3) * tanh_f(c_state);
      hbuf[1 - p][ch][uown] = (_Float16)hval;
      if (t == T_STEPS - 1) h2last[(size_t)(b0 + ch) * HID + uown] = hval;
      bar_lds();
    }
  }
}

// ------------------------------------------------------------- fc head ----
__global__ __launch_bounds__(128) void fc_head(
    const float* __restrict__ h2last, const float* __restrict__ fc1w,
    const float* __restrict__ fc1b, const float* __restrict__ fc2w,
    const float* __restrict__ fc2b, float* __restrict__ out) {
  __shared__ float hb[128];
  __shared__ float part[2];
  const int b = blockIdx.x, j = threadIdx.x;
  hb[j] = h2last[(size_t)b * HID + j];
  __syncthreads();
  const float* wr = fc1w + j * HID;
  float acc = 0.f;
  #pragma unroll 8
  for (int d = 0; d < HID; ++d) acc += wr[d] * hb[d];
  float v = fmaxf(acc + fc1b[j], 0.f) * fc2w[j];
  #pragma unroll
  for (int s = 32; s > 0; s >>= 1) v += __shfl_down(v, s);
  if ((j & 63) == 0) part[j >> 6] = v;
  __syncthreads();
  if (j == 0) out[b] = part[0] + part[1] + fc2b[0];
}

// -------------------------------------------------------------- launch ----
extern "C" void kernel_launch(void* const* d_in, const int* in_sizes, int n_in,
                              void* d_out, int out_size, void* d_ws, size_t ws_size,
                              hipStream_t stream) {
  const float* x    = (const float*)d_in[0];
  const float* Wih0 = (const float*)d_in[1];
  const float* Whh0 = (const float*)d_in[2];
  const float* bih0 = (const float*)d_in[3];
  const float* bhh0 = (const float*)d_in[4];
  const float* Wih1 = (const float*)d_in[5];
  const float* Whh1 = (const float*)d_in[6];
  const float* bih1 = (const float*)d_in[7];
  const float* bhh1 = (const float*)d_in[8];
  const float* fc1w = (const float*)d_in[9];
  const float* fc1b = (const float*)d_in[10];
  const float* fc2w = (const float*)d_in[11];
  const float* fc2b = (const float*)d_in[12];
  float* out = (float*)d_out;

  char* ws = (char*)d_ws;
  const size_t OFF_HS0 = 0;                    // 512*512*128*2 = 64 MiB
  const size_t OFF_WC0 = 67108864;             // 512*192*2
  const size_t OFF_WC1 = OFF_WC0 + 196608;     // 512*256*2
  const size_t OFF_B0  = OFF_WC1 + 262144;     // 512*4
  const size_t OFF_B1  = OFF_B0 + 2048;
  const size_t OFF_H2L = OFF_B1 + 2048;        // 512*128*4
  const size_t OFF_FLG = OFF_H2L + 262144;     // 128*4

  _Float16* hs0    = (_Float16*)(ws + OFF_HS0);
  _Float16* Wcat0  = (_Float16*)(ws + OFF_WC0);
  _Float16* Wcat1  = (_Float16*)(ws + OFF_WC1);
  float*    bias0  = (float*)(ws + OFF_B0);
  float*    bias1  = (float*)(ws + OFF_B1);
  float*    h2last = (float*)(ws + OFF_H2L);
  int*      flags  = (int*)(ws + OFF_FLG);

  prep_w<<<512, 256, 0, stream>>>(Wih0, Whh0, bih0, bhh0, Wih1, Whh1, bih1, bhh1,
                                  Wcat0, Wcat1, bias0, bias1, flags);
  lstm_pc<<<256, 512, 0, stream>>>(x, Wcat0, bias0, Wcat1, bias1, hs0, h2last, flags);
  fc_head<<<512, 128, 0, stream>>>(h2last, fc1w, fc1b, fc2w, fc2b, out);
}